// Round 16
// baseline (177.969 us; speedup 1.0000x reference)
//
#include <hip/hip_runtime.h>
#include <stdint.h>

#define S_LEN 2048
#define BATCH 2
#define DM 1024
#define NH 16
#define DH 64
#define MROWS 4096  // BATCH * S_LEN

typedef unsigned short u16;
typedef unsigned int u32;
typedef __attribute__((ext_vector_type(8))) short bf16x8;
typedef __attribute__((ext_vector_type(4))) float f32x4;
typedef __attribute__((ext_vector_type(2))) unsigned u32x2;

union pack8 { u32 w[4]; bf16x8 v8; };

__device__ inline u16 f2bf(float f) {
  union { float f; unsigned u; } v; v.f = f;
  unsigned u = v.u;
  unsigned r = u + 0x7fffu + ((u >> 16) & 1u);
  return (u16)(r >> 16);
}

__device__ inline u32 pkbf(float lo, float hi) {
  u32 r;
  asm("v_cvt_pk_bf16_f32 %0, %1, %2" : "=v"(r) : "v"(lo), "v"(hi));
  return r;
}

__device__ inline float bf2f(short s) {
  union { u32 u; float f; } c; c.u = ((u32)(u16)s) << 16;
  return c.f;
}

// async global -> LDS, 16B per lane; LDS dest is wave-uniform base + lane*16
__device__ __forceinline__ void gload_lds16(const u16* g, u16* l) {
  __builtin_amdgcn_global_load_lds(
      (const __attribute__((address_space(1))) u32*)g,
      (__attribute__((address_space(3))) u32*)l, 16, 0, 0);
}

// ---------------- fp32 -> bf16 conversion for x, Wq, Wk, Wv, Wo ----------------
__global__ void convert_k(const float* __restrict__ x, const float* __restrict__ wq,
                          const float* __restrict__ wk, const float* __restrict__ wv,
                          const float* __restrict__ wo, u16* __restrict__ xb,
                          u16* __restrict__ wb) {
  int i = blockIdx.x * blockDim.x + threadIdx.x;
  const int total = (MROWS * DM + 4 * DM * DM) / 4;  // 2,097,152 float4 groups
  if (i >= total) return;
  int e = i * 4;
  const float* src;
  u16* dst;
  if (e < MROWS * DM) {
    src = x + e; dst = xb + e;
  } else {
    int j = e - MROWS * DM;
    int w = j >> 20;
    int o = j & ((1 << 20) - 1);
    src = (w == 0) ? wq + o : (w == 1) ? wk + o : (w == 2) ? wv + o : wo + o;
    dst = wb + j;
  }
  float4 v = *(const float4*)src;
  uint2 r;
  r.x = (unsigned)f2bf(v.x) | ((unsigned)f2bf(v.y) << 16);
  r.y = (unsigned)f2bf(v.z) | ((unsigned)f2bf(v.w) << 16);
  *(uint2*)dst = r;
}

// ---------------- RoPE cos/sin table [S][32]; also zero kmax[32] ----------------
__global__ void rope_k(float2* __restrict__ tab, float* __restrict__ kmax) {
  int i = blockIdx.x * blockDim.x + threadIdx.x;
  if (i < 32) kmax[i] = 0.f;
  if (i >= S_LEN * 32) return;
  int s = i >> 5, p = i & 31;
  float inv = expf(-(float)p * 0.28782313662425575f);  // ln(10000)/32
  float a = (float)s * inv;
  tab[i] = make_float2(cosf(a), sinf(a));
}

// ---------------- per-bh max row norm of K (for static softmax bound) ----------------
__global__ void knorm_k(const u16* __restrict__ K, float* __restrict__ kmax) {
  const int row = blockIdx.x * 256 + threadIdx.x;  // 65536 rows = B*H*S
  const int bh = row >> 11;
  const u16* p = K + (size_t)row * DH;
  float ss = 0.f;
#pragma unroll
  for (int i = 0; i < 8; i++) {
    bf16x8 v = *(const bf16x8*)(p + i * 8);
#pragma unroll
    for (int j = 0; j < 8; j++) { float f = bf2f(v[j]); ss += f * f; }
  }
  float kn = sqrtf(ss);
#pragma unroll
  for (int d = 1; d < 64; d <<= 1) kn = fmaxf(kn, __shfl_xor(kn, d));
  if ((threadIdx.x & 63) == 0)
    atomicMax((unsigned*)(kmax + bh), __float_as_uint(kn));
}

// ---------------- GEMM: C = A @ W^T + bias, fused epilogues ----------------
// m97 structure + T4 counted vmcnt: [2]-double-buffered linear LDS tiles staged
// via global_load_lds; next K-step's 4 loads stay IN FLIGHT across both barriers
// (s_waitcnt vmcnt(4), never 0 in the main loop) — removes the __syncthreads
// vmcnt(0) drain that nullified the prefetch.
// mode 0: Q -> rope,*0.125*log2e bf16 [B,H,S,Dh]; 1: K -> rope; 2: V s-permuted
// [B,H,Dh,S]; 3: O -> fp32 [M,DM]
__launch_bounds__(256)
__global__ void gemm_k(const u16* __restrict__ A,
                       const u16* __restrict__ w0, const u16* __restrict__ w1,
                       const u16* __restrict__ w2,
                       const float* __restrict__ b0, const float* __restrict__ b1,
                       const float* __restrict__ b2,
                       const float2* __restrict__ rope,
                       void* __restrict__ o0, void* __restrict__ o1, void* __restrict__ o2,
                       int mode0) {
  const int mode = mode0 + (int)(blockIdx.x >> 8);
  const int tile = blockIdx.x & 255;
  const int mt = tile >> 3, nt = tile & 7;
  const int mbase = mt * 128, nbase = nt * 128;
  const u16* W = (mode == 1) ? w1 : (mode == 2) ? w2 : w0;
  const float* bias = (mode == 1) ? b1 : (mode == 2) ? b2 : b0;
  void* outp = (mode == 1) ? o1 : (mode == 2) ? o2 : o0;

  __shared__ u16 As[2][128 * 32];  // 2 x 8 KB, linear
  __shared__ u16 Bs[2][128 * 32];

  const int t = threadIdx.x;
  const int lane = t & 63, wvi = t >> 6;
  const int lr = lane & 15, lg = lane >> 4;
  const int wm = (wvi >> 1) * 64, wn = (wvi & 1) * 64;

  f32x4 acc[4][4] = {};
  const int srow = t >> 2;        // 0..63 (row within half-tile)
  const int scol = (t & 3) * 8;   // 0,8,16,24 u16

  // prologue: stage k=0 into buf 0
  gload_lds16(A + (size_t)(mbase + srow) * DM + scol, &As[0][wvi * 512]);
  gload_lds16(A + (size_t)(mbase + 64 + srow) * DM + scol, &As[0][2048 + wvi * 512]);
  gload_lds16(W + (size_t)(nbase + srow) * DM + scol, &Bs[0][wvi * 512]);
  gload_lds16(W + (size_t)(nbase + 64 + srow) * DM + scol, &Bs[0][2048 + wvi * 512]);

  for (int kk = 0; kk < DM; kk += 32) {
    const int b = (kk >> 5) & 1;
    if (kk + 32 < DM) {  // stage next K-step into the other buffer; keep in flight
      gload_lds16(A + (size_t)(mbase + srow) * DM + kk + 32 + scol, &As[b ^ 1][wvi * 512]);
      gload_lds16(A + (size_t)(mbase + 64 + srow) * DM + kk + 32 + scol, &As[b ^ 1][2048 + wvi * 512]);
      gload_lds16(W + (size_t)(nbase + srow) * DM + kk + 32 + scol, &Bs[b ^ 1][wvi * 512]);
      gload_lds16(W + (size_t)(nbase + 64 + srow) * DM + kk + 32 + scol, &Bs[b ^ 1][2048 + wvi * 512]);
      asm volatile("s_waitcnt vmcnt(4)" ::: "memory");  // own stage(k) done
    } else {
      asm volatile("s_waitcnt vmcnt(0)" ::: "memory");
    }
    __builtin_amdgcn_s_barrier();  // everyone's stage(k) done

    bf16x8 af[4], bfr[4];
#pragma unroll
    for (int mi = 0; mi < 4; mi++)
      af[mi] = *(const bf16x8*)&As[b][(wm + mi * 16 + lr) * 32 + lg * 8];
#pragma unroll
    for (int ni = 0; ni < 4; ni++)
      bfr[ni] = *(const bf16x8*)&Bs[b][(wn + ni * 16 + lr) * 32 + lg * 8];
#pragma unroll
    for (int mi = 0; mi < 4; mi++)
#pragma unroll
      for (int ni = 0; ni < 4; ni++)
        acc[mi][ni] = __builtin_amdgcn_mfma_f32_16x16x32_bf16(af[mi], bfr[ni], acc[mi][ni], 0, 0, 0);

    __builtin_amdgcn_s_barrier();  // all reads done before buf reuse
    asm volatile("" ::: "memory");
  }

#pragma unroll
  for (int ni = 0; ni < 4; ni++) {
    const int col = nbase + wn + ni * 16 + lr;
    const float bv = bias[col];
#pragma unroll
    for (int mi = 0; mi < 4; mi++) {
      const int row0 = mbase + wm + mi * 16 + lg * 4;
      f32x4 v = acc[mi][ni];
#pragma unroll
      for (int r = 0; r < 4; r++) {
        float val = v[r] + bv;
        const int row = row0 + r;
        if (mode <= 1) {
          float nb = __shfl_xor(val, 1);
          const int d = col & 63, p = d >> 1, s = row & (S_LEN - 1);
          float2 cs = rope[s * 32 + p];
          float ov = (d & 1) ? (nb * cs.y + val * cs.x) : (val * cs.x - nb * cs.y);
          if (mode == 0) ov *= 0.18033688011112042f;  // 1/sqrt(Dh) * log2(e)
          const int b = row >> 11, h = col >> 6;
          ((u16*)outp)[((size_t)(b * NH + h) * S_LEN + s) * DH + d] = f2bf(ov);
        } else if (mode == 2) {
          const int b = row >> 11, h = col >> 6, d = col & 63, s = row & (S_LEN - 1);
          const int j = s & 31;
          const int pos = (s & ~31) + (((j & 15) >> 2) << 3) + ((j >> 4) << 2) + (j & 3);
          ((u16*)outp)[((size_t)(b * NH + h) * DH + d) * S_LEN + pos] = f2bf(val);
        } else {
          ((float*)outp)[(size_t)row * DM + col] = val;
        }
      }
    }
  }
}

// ---- static-bound softmax + PV for one q-group: accumulate into o[4] ----
__device__ __forceinline__ void sm_pv(const float a[8], float m, float& l,
                                      bf16x8 v0, bf16x8 v1, bf16x8 v2, bf16x8 v3,
                                      f32x4* o) {
  float p[8];
#pragma unroll
  for (int r = 0; r < 8; r++) p[r] = __builtin_amdgcn_exp2f(a[r] - m);
  l += ((p[0] + p[1]) + (p[2] + p[3])) + ((p[4] + p[5]) + (p[6] + p[7]));
  pack8 pu;
  pu.w[0] = pkbf(p[0], p[1]);
  pu.w[1] = pkbf(p[2], p[3]);
  pu.w[2] = pkbf(p[4], p[5]);
  pu.w[3] = pkbf(p[6], p[7]);
  o[0] = __builtin_amdgcn_mfma_f32_16x16x32_bf16(v0, pu.v8, o[0], 0, 0, 0);
  o[1] = __builtin_amdgcn_mfma_f32_16x16x32_bf16(v1, pu.v8, o[1], 0, 0, 0);
  o[2] = __builtin_amdgcn_mfma_f32_16x16x32_bf16(v2, pu.v8, o[2], 0, 0, 0);
  o[3] = __builtin_amdgcn_mfma_f32_16x16x32_bf16(v3, pu.v8, o[3], 0, 0, 0);
}

// ---------------- causal flash attention: LDS-staged K/V + counted vmcnt ----------------
// R15 structure; T4 fix: the next step's 2 global_load_lds stay in flight across
// both barriers (s_waitcnt vmcnt(2), never 0 in the loop) instead of being drained
// by __syncthreads' vmcnt(0) — load latency now hides under the previous step's
// compute. K swizzle (row&7), V swizzle ((row>>1)&3) unchanged (conflicts ~0).
__launch_bounds__(256)
__global__ void attn_k(const u16* __restrict__ Q, const u16* __restrict__ K,
                       const u16* __restrict__ Vt, u16* __restrict__ Oo,
                       const float* __restrict__ kmax) {
  const int bh = blockIdx.x & 31;
  const int g = 15 - (int)(blockIdx.x >> 5);   // longest-first
  const int tid = threadIdx.x;
  const int w = tid >> 6;
  const int lane = tid & 63;
  const int lr = lane & 15, lg = lane >> 4;
  const int tile = g * 4 + w;
  const int qbase = tile * 32;
  const int nst = g * 4 + 4;                   // steps for the whole block

  __shared__ u16 Ks[2][2048];                  // [buf][32 x 64] bf16, swizzled
  __shared__ u16 Vs[2][2048];                  // [buf][64 x 32] bf16, swizzled

  const u16* Kg = K + (size_t)bh * S_LEN * DH;
  const u16* Vg = Vt + (size_t)bh * DH * S_LEN;

  // staging indices (tid-static)
  const int kr = tid >> 3, kcB = (tid & 7) << 4;
  const int vr = tid >> 2, vcB = (tid & 3) << 4;
  const int ksrcoff = ((kcB ^ ((kr & 7) << 4)) >> 1);
  const int vsrcoff = ((vcB ^ (((vr >> 1) & 3) << 4)) >> 1);

  // ---- Q fragments + static softmax bound ----
  const size_t qoff = ((size_t)bh * S_LEN + qbase + lr) * DH + lg * 8;
  const bf16x8 qA0 = *(const bf16x8*)(Q + qoff);
  const bf16x8 qA1 = *(const bf16x8*)(Q + qoff + 32);
  const bf16x8 qB0 = *(const bf16x8*)(Q + qoff + 16 * DH);
  const bf16x8 qB1 = *(const bf16x8*)(Q + qoff + 16 * DH + 32);

  float ssA = 0.f, ssB = 0.f;
#pragma unroll
  for (int j = 0; j < 8; j++) {
    float a0 = bf2f(qA0[j]), a1 = bf2f(qA1[j]);
    float b0 = bf2f(qB0[j]), b1 = bf2f(qB1[j]);
    ssA += a0 * a0 + a1 * a1;
    ssB += b0 * b0 + b1 * b1;
  }
  ssA += __shfl_xor(ssA, 16); ssA += __shfl_xor(ssA, 32);
  ssB += __shfl_xor(ssB, 16); ssB += __shfl_xor(ssB, 32);
  const float kmx = kmax[bh];
  const float mA = sqrtf(ssA) * kmx;
  const float mB = sqrtf(ssB) * kmx;

  f32x4 oA[4] = {}, oB[4] = {};
  float lA = 0.f, lB = 0.f;
  const f32x4 zero = {};

  // fragment read offsets (swizzled)
  const int kmsk = (lr & 7) << 4;
  const int k00 = lr * 64 + (((lg << 4)) ^ kmsk) / 2;
  const int k01 = lr * 64 + ((64 + (lg << 4)) ^ kmsk) / 2;
  const int k10 = (16 + lr) * 64 + (((lg << 4)) ^ kmsk) / 2;
  const int k11 = (16 + lr) * 64 + ((64 + (lg << 4)) ^ kmsk) / 2;
  const int vmsk = ((lr >> 1) & 3) << 4;
  const int vo = ((lg << 4) ^ vmsk) / 2;

  // ---- prologue: stage step 0 into buf 0 ----
  gload_lds16(Kg + (size_t)kr * DH + ksrcoff, &Ks[0][w << 9]);
  gload_lds16(Vg + (size_t)vr * S_LEN + vsrcoff, &Vs[0][w << 9]);

  for (int s = 0; s < nst; ++s) {
    const int b = s & 1;
    if (s + 1 < nst) {  // stage next step; keep its 2 loads in flight
      gload_lds16(Kg + (size_t)((s + 1) * 32 + kr) * DH + ksrcoff, &Ks[b ^ 1][w << 9]);
      gload_lds16(Vg + (size_t)vr * S_LEN + (s + 1) * 32 + vsrcoff, &Vs[b ^ 1][w << 9]);
      asm volatile("s_waitcnt vmcnt(2)" ::: "memory");  // own stage(s) done
    } else {
      asm volatile("s_waitcnt vmcnt(0)" ::: "memory");
    }
    __builtin_amdgcn_s_barrier();  // everyone's stage(s) done

    const u16* Kb = Ks[b];
    const u16* Vb = Vs[b];
    bf16x8 kc0 = *(const bf16x8*)&Kb[k00];
    bf16x8 kc1 = *(const bf16x8*)&Kb[k01];
    bf16x8 kc2 = *(const bf16x8*)&Kb[k10];
    bf16x8 kc3 = *(const bf16x8*)&Kb[k11];
    bf16x8 v0 = *(const bf16x8*)&Vb[(lr) * 32 + vo];
    bf16x8 v1 = *(const bf16x8*)&Vb[(16 + lr) * 32 + vo];
    bf16x8 v2 = *(const bf16x8*)&Vb[(32 + lr) * 32 + vo];
    bf16x8 v3 = *(const bf16x8*)&Vb[(48 + lr) * 32 + vo];

    f32x4 s0A = __builtin_amdgcn_mfma_f32_16x16x32_bf16(kc0, qA0, zero, 0, 0, 0);
    s0A = __builtin_amdgcn_mfma_f32_16x16x32_bf16(kc1, qA1, s0A, 0, 0, 0);
    f32x4 s1A = __builtin_amdgcn_mfma_f32_16x16x32_bf16(kc2, qA0, zero, 0, 0, 0);
    s1A = __builtin_amdgcn_mfma_f32_16x16x32_bf16(kc3, qA1, s1A, 0, 0, 0);
    f32x4 s0B = __builtin_amdgcn_mfma_f32_16x16x32_bf16(kc0, qB0, zero, 0, 0, 0);
    s0B = __builtin_amdgcn_mfma_f32_16x16x32_bf16(kc1, qB1, s0B, 0, 0, 0);
    f32x4 s1B = __builtin_amdgcn_mfma_f32_16x16x32_bf16(kc2, qB0, zero, 0, 0, 0);
    s1B = __builtin_amdgcn_mfma_f32_16x16x32_bf16(kc3, qB1, s1B, 0, 0, 0);

    // generic causal mask (passes automatically for steps below the diagonal)
    const int qrelA = qbase + lr - (s << 5) - (lg << 2);
    const int qrelB = qrelA + 16;
    float aA[8], aB[8];
#pragma unroll
    for (int r = 0; r < 4; r++) {
      aA[r]     = (r <= qrelA)      ? s0A[r] : -__builtin_inff();
      aA[4 + r] = (r + 16 <= qrelA) ? s1A[r] : -__builtin_inff();
      aB[r]     = (r <= qrelB)      ? s0B[r] : -__builtin_inff();
      aB[4 + r] = (r + 16 <= qrelB) ? s1B[r] : -__builtin_inff();
    }
    sm_pv(aA, mA, lA, v0, v1, v2, v3, oA);
    sm_pv(aB, mB, lB, v0, v1, v2, v3, oB);

    __builtin_amdgcn_s_barrier();  // all reads of buf b done before re-stage
    asm volatile("" ::: "memory");
  }

  // ---- epilogue: lane holds q=lr, d = dt*16 + lg*4 + r ----
  lA += __shfl_xor(lA, 16); lA += __shfl_xor(lA, 32);
  lB += __shfl_xor(lB, 16); lB += __shfl_xor(lB, 32);
  const float rlA = __builtin_amdgcn_rcpf(lA);
  const float rlB = __builtin_amdgcn_rcpf(lB);

  const int bb = bh >> 4, h = bh & 15;
  const size_t obaseA = ((size_t)bb * S_LEN + qbase + lr) * DM + h * DH;
  const size_t obaseB = obaseA + (size_t)16 * DM;
#pragma unroll
  for (int dt = 0; dt < 4; dt++) {
    u32x2 pkA, pkB;
    pkA.x = pkbf(oA[dt][0] * rlA, oA[dt][1] * rlA);
    pkA.y = pkbf(oA[dt][2] * rlA, oA[dt][3] * rlA);
    pkB.x = pkbf(oB[dt][0] * rlB, oB[dt][1] * rlB);
    pkB.y = pkbf(oB[dt][2] * rlB, oB[dt][3] * rlB);
    *(u32x2*)(Oo + obaseA + dt * 16 + lg * 4) = pkA;
    *(u32x2*)(Oo + obaseB + dt * 16 + lg * 4) = pkB;
  }
}

// ---------------- host launcher ----------------
extern "C" void kernel_launch(void* const* d_in, const int* in_sizes, int n_in,
                              void* d_out, int out_size, void* d_ws, size_t ws_size,
                              hipStream_t stream) {
  const float* x  = (const float*)d_in[0];
  const float* Wq = (const float*)d_in[1];
  const float* bq = (const float*)d_in[2];
  const float* Wk = (const float*)d_in[3];
  const float* bk = (const float*)d_in[4];
  const float* Wv = (const float*)d_in[5];
  const float* bv = (const float*)d_in[6];
  const float* Wo = (const float*)d_in[7];
  const float* bo = (const float*)d_in[8];

  char* ws = (char*)d_ws;
  u16* xb    = (u16*)(ws);                 // 8 MB  [4096,1024] bf16
  u16* wb    = (u16*)(ws + (8u << 20));    // 8 MB  Wq,Wk,Wv,Wo bf16
  u16* Qb    = (u16*)(ws + (16u << 20));   // 8 MB  [B,H,S,Dh]
  u16* Kb    = (u16*)(ws + (24u << 20));   // 8 MB  [B,H,S,Dh]
  u16* Vtb   = (u16*)(ws + (32u << 20));   // 8 MB  [B,H,Dh,S] (s-permuted)
  u16* AOb   = (u16*)(ws + (40u << 20));   // 8 MB  [B*S, DM]
  float2* rt = (float2*)(ws + (48u << 20));            // 512 KB rope table
  float* kmx = (float*)(ws + (48u << 20) + (512u << 10));  // 128 B kmax[32]

  convert_k<<<8192, 256, 0, stream>>>(x, Wq, Wk, Wv, Wo, xb, wb);
  rope_k<<<256, 256, 0, stream>>>(rt, kmx);
  gemm_k<<<768, 256, 0, stream>>>(xb, wb, wb + (1u << 20), wb + (2u << 20),
                                  bq, bk, bv, rt, Qb, Kb, Vtb, 0);
  knorm_k<<<256, 256, 0, stream>>>(Kb, kmx);
  attn_k<<<512, 256, 0, stream>>>(Qb, Kb, Vtb, AOb, kmx);
  gemm_k<<<256, 256, 0, stream>>>(AOb, wb + (3u << 20), wb + (3u << 20), wb + (3u << 20),
                                  bo, bo, bo, rt, d_out, d_out, d_out, 3);
}

// Round 17
// 150.717 us; speedup vs baseline: 1.1808x; 1.1808x over previous
//
#include <hip/hip_runtime.h>
#include <stdint.h>

#define S_LEN 2048
#define BATCH 2
#define DM 1024
#define NH 16
#define DH 64
#define MROWS 4096  // BATCH * S_LEN

typedef unsigned short u16;
typedef unsigned int u32;
typedef __attribute__((ext_vector_type(8))) short bf16x8;
typedef __attribute__((ext_vector_type(4))) float f32x4;
typedef __attribute__((ext_vector_type(2))) unsigned u32x2;

union pack8 { u32 w[4]; bf16x8 v8; };

__device__ inline u16 f2bf(float f) {
  union { float f; unsigned u; } v; v.f = f;
  unsigned u = v.u;
  unsigned r = u + 0x7fffu + ((u >> 16) & 1u);
  return (u16)(r >> 16);
}

__device__ inline u32 pkbf(float lo, float hi) {
  u32 r;
  asm("v_cvt_pk_bf16_f32 %0, %1, %2" : "=v"(r) : "v"(lo), "v"(hi));
  return r;
}

__device__ inline float bf2f(short s) {
  union { u32 u; float f; } c; c.u = ((u32)(u16)s) << 16;
  return c.f;
}

// async global -> LDS, 16B per lane; LDS dest is wave-uniform base + lane*16
__device__ __forceinline__ void gload_lds16(const u16* g, u16* l) {
  __builtin_amdgcn_global_load_lds(
      (const __attribute__((address_space(1))) u32*)g,
      (__attribute__((address_space(3))) u32*)l, 16, 0, 0);
}

// ---------------- fp32 -> bf16 conversion for x, Wq, Wk, Wv, Wo ----------------
__global__ void convert_k(const float* __restrict__ x, const float* __restrict__ wq,
                          const float* __restrict__ wk, const float* __restrict__ wv,
                          const float* __restrict__ wo, u16* __restrict__ xb,
                          u16* __restrict__ wb) {
  int i = blockIdx.x * blockDim.x + threadIdx.x;
  const int total = (MROWS * DM + 4 * DM * DM) / 4;  // 2,097,152 float4 groups
  if (i >= total) return;
  int e = i * 4;
  const float* src;
  u16* dst;
  if (e < MROWS * DM) {
    src = x + e; dst = xb + e;
  } else {
    int j = e - MROWS * DM;
    int w = j >> 20;
    int o = j & ((1 << 20) - 1);
    src = (w == 0) ? wq + o : (w == 1) ? wk + o : (w == 2) ? wv + o : wo + o;
    dst = wb + j;
  }
  float4 v = *(const float4*)src;
  uint2 r;
  r.x = (unsigned)f2bf(v.x) | ((unsigned)f2bf(v.y) << 16);
  r.y = (unsigned)f2bf(v.z) | ((unsigned)f2bf(v.w) << 16);
  *(uint2*)dst = r;
}

// ---------------- RoPE cos/sin table [S][32]; also zero kmax[32] ----------------
__global__ void rope_k(float2* __restrict__ tab, float* __restrict__ kmax) {
  int i = blockIdx.x * blockDim.x + threadIdx.x;
  if (i < 32) kmax[i] = 0.f;
  if (i >= S_LEN * 32) return;
  int s = i >> 5, p = i & 31;
  float inv = expf(-(float)p * 0.28782313662425575f);  // ln(10000)/32
  float a = (float)s * inv;
  tab[i] = make_float2(cosf(a), sinf(a));
}

// ---------------- per-bh max row norm of K (for static softmax bound) ----------------
__global__ void knorm_k(const u16* __restrict__ K, float* __restrict__ kmax) {
  const int row = blockIdx.x * 256 + threadIdx.x;  // 65536 rows = B*H*S
  const int bh = row >> 11;
  const u16* p = K + (size_t)row * DH;
  float ss = 0.f;
#pragma unroll
  for (int i = 0; i < 8; i++) {
    bf16x8 v = *(const bf16x8*)(p + i * 8);
#pragma unroll
    for (int j = 0; j < 8; j++) { float f = bf2f(v[j]); ss += f * f; }
  }
  float kn = sqrtf(ss);
#pragma unroll
  for (int d = 1; d < 64; d <<= 1) kn = fmaxf(kn, __shfl_xor(kn, d));
  if ((threadIdx.x & 63) == 0)
    atomicMax((unsigned*)(kmax + bh), __float_as_uint(kn));
}

// ---------------- GEMM: C = A @ W^T + bias, fused epilogues (R15 form) ----------------
// m97 structure: linear [128][32] LDS tiles staged via global_load_lds width-16,
// 2-barrier K-loop (R16's counted-vmcnt variant regressed — m141 lesson: asm
// memory fences defeat the compiler's own scheduling; reverted).
__launch_bounds__(256)
__global__ void gemm_k(const u16* __restrict__ A,
                       const u16* __restrict__ w0, const u16* __restrict__ w1,
                       const u16* __restrict__ w2,
                       const float* __restrict__ b0, const float* __restrict__ b1,
                       const float* __restrict__ b2,
                       const float2* __restrict__ rope,
                       void* __restrict__ o0, void* __restrict__ o1, void* __restrict__ o2,
                       int mode0) {
  const int mode = mode0 + (int)(blockIdx.x >> 8);
  const int tile = blockIdx.x & 255;
  const int mt = tile >> 3, nt = tile & 7;
  const int mbase = mt * 128, nbase = nt * 128;
  const u16* W = (mode == 1) ? w1 : (mode == 2) ? w2 : w0;
  const float* bias = (mode == 1) ? b1 : (mode == 2) ? b2 : b0;
  void* outp = (mode == 1) ? o1 : (mode == 2) ? o2 : o0;

  __shared__ u16 As[128 * 32];  // 8 KB, linear (global_load_lds writes linearly)
  __shared__ u16 Bs[128 * 32];

  const int t = threadIdx.x;
  const int lane = t & 63, wvi = t >> 6;
  const int lr = lane & 15, lg = lane >> 4;
  const int wm = (wvi >> 1) * 64, wn = (wvi & 1) * 64;

  f32x4 acc[4][4] = {};
  const int srow = t >> 2;        // 0..63 (row within half-tile)
  const int scol = (t & 3) * 8;   // 0,8,16,24 u16

  for (int kk = 0; kk < DM; kk += 32) {
    gload_lds16(A + (size_t)(mbase + srow) * DM + kk + scol, &As[wvi * 512]);
    gload_lds16(A + (size_t)(mbase + 64 + srow) * DM + kk + scol, &As[2048 + wvi * 512]);
    gload_lds16(W + (size_t)(nbase + srow) * DM + kk + scol, &Bs[wvi * 512]);
    gload_lds16(W + (size_t)(nbase + 64 + srow) * DM + kk + scol, &Bs[2048 + wvi * 512]);
    __syncthreads();  // vmcnt(0) drain: tiles staged

    bf16x8 af[4], bfr[4];
#pragma unroll
    for (int mi = 0; mi < 4; mi++)
      af[mi] = *(const bf16x8*)&As[(wm + mi * 16 + lr) * 32 + lg * 8];
#pragma unroll
    for (int ni = 0; ni < 4; ni++)
      bfr[ni] = *(const bf16x8*)&Bs[(wn + ni * 16 + lr) * 32 + lg * 8];
#pragma unroll
    for (int mi = 0; mi < 4; mi++)
#pragma unroll
      for (int ni = 0; ni < 4; ni++)
        acc[mi][ni] = __builtin_amdgcn_mfma_f32_16x16x32_bf16(af[mi], bfr[ni], acc[mi][ni], 0, 0, 0);
    __syncthreads();  // all reads done before next stage overwrites
  }

#pragma unroll
  for (int ni = 0; ni < 4; ni++) {
    const int col = nbase + wn + ni * 16 + lr;
    const float bv = bias[col];
#pragma unroll
    for (int mi = 0; mi < 4; mi++) {
      const int row0 = mbase + wm + mi * 16 + lg * 4;
      f32x4 v = acc[mi][ni];
#pragma unroll
      for (int r = 0; r < 4; r++) {
        float val = v[r] + bv;
        const int row = row0 + r;
        if (mode <= 1) {
          float nb = __shfl_xor(val, 1);
          const int d = col & 63, p = d >> 1, s = row & (S_LEN - 1);
          float2 cs = rope[s * 32 + p];
          float ov = (d & 1) ? (nb * cs.y + val * cs.x) : (val * cs.x - nb * cs.y);
          if (mode == 0) ov *= 0.18033688011112042f;  // 1/sqrt(Dh) * log2(e)
          const int b = row >> 11, h = col >> 6;
          ((u16*)outp)[((size_t)(b * NH + h) * S_LEN + s) * DH + d] = f2bf(ov);
        } else if (mode == 2) {
          const int b = row >> 11, h = col >> 6, d = col & 63, s = row & (S_LEN - 1);
          const int j = s & 31;
          const int pos = (s & ~31) + (((j & 15) >> 2) << 3) + ((j >> 4) << 2) + (j & 3);
          ((u16*)outp)[((size_t)(b * NH + h) * DH + d) * S_LEN + pos] = f2bf(val);
        } else {
          ((float*)outp)[(size_t)row * DM + col] = val;
        }
      }
    }
  }
}

// ---- static-bound softmax + PV for one q-group: accumulate into o[4] ----
__device__ __forceinline__ void sm_pv(const float a[8], float m, float& l,
                                      bf16x8 v0, bf16x8 v1, bf16x8 v2, bf16x8 v3,
                                      f32x4* o) {
  float p[8];
#pragma unroll
  for (int r = 0; r < 8; r++) p[r] = __builtin_amdgcn_exp2f(a[r] - m);
  l += ((p[0] + p[1]) + (p[2] + p[3])) + ((p[4] + p[5]) + (p[6] + p[7]));
  pack8 pu;
  pu.w[0] = pkbf(p[0], p[1]);
  pu.w[1] = pkbf(p[2], p[3]);
  pu.w[2] = pkbf(p[4], p[5]);
  pu.w[3] = pkbf(p[6], p[7]);
  o[0] = __builtin_amdgcn_mfma_f32_16x16x32_bf16(v0, pu.v8, o[0], 0, 0, 0);
  o[1] = __builtin_amdgcn_mfma_f32_16x16x32_bf16(v1, pu.v8, o[1], 0, 0, 0);
  o[2] = __builtin_amdgcn_mfma_f32_16x16x32_bf16(v2, pu.v8, o[2], 0, 0, 0);
  o[3] = __builtin_amdgcn_mfma_f32_16x16x32_bf16(v3, pu.v8, o[3], 0, 0, 0);
}

// ---------------- causal flash attention: 1 wave/block, barrier-FREE pipeline ----------------
// Single wave owns one 32-row q-tile and stages its own K/V tiles into private
// LDS double-buffers via global_load_lds. NO barriers anywhere: the wave's own
// s_waitcnt vmcnt(8) is sufficient for LDS visibility, so the next step's 8
// loads stay in flight under the whole compute phase (true T4, no lockstep).
// 2048 blocks (16 KB LDS each) -> 8 independent streams/CU; resident tile set
// per CU spans lengths (stride-8 spacing) -> built-in load balance.
__launch_bounds__(64)
__global__ void attn_k(const u16* __restrict__ Q, const u16* __restrict__ K,
                       const u16* __restrict__ Vt, u16* __restrict__ Oo,
                       const float* __restrict__ kmax) {
  const int bh = blockIdx.x & 31;
  const int tile = (int)(blockIdx.x >> 5);     // 0..63
  const int qbase = tile * 32;
  const int nst = tile + 1;                    // 32-wide kv steps; last masked
  const int lane = threadIdx.x;
  const int lr = lane & 15, lg = lane >> 4;

  __shared__ u16 Ks[2][2048];                  // [buf][32 x 64] bf16, swizzled
  __shared__ u16 Vs[2][2048];                  // [buf][64 x 32] bf16, swizzled

  const u16* Kg = K + (size_t)bh * S_LEN * DH;
  const u16* Vg = Vt + (size_t)bh * DH * S_LEN;

  // staging constants (lane-static; swizzle masks invariant across issues)
  const int krow = lane >> 3;                          // + 8*i
  const int ksoff = ((((lane & 7) << 4) ^ ((lane >> 3) << 4)) >> 1);  // u16
  const int vrow = lane >> 2;                          // + 16*i
  const int vsoff = ((((lane & 3) << 4) ^ (((lane >> 3) & 3) << 4)) >> 1);

  // ---- Q fragments + static softmax bound ----
  const size_t qoff = ((size_t)bh * S_LEN + qbase + lr) * DH + lg * 8;
  const bf16x8 qA0 = *(const bf16x8*)(Q + qoff);
  const bf16x8 qA1 = *(const bf16x8*)(Q + qoff + 32);
  const bf16x8 qB0 = *(const bf16x8*)(Q + qoff + 16 * DH);
  const bf16x8 qB1 = *(const bf16x8*)(Q + qoff + 16 * DH + 32);

  float ssA = 0.f, ssB = 0.f;
#pragma unroll
  for (int j = 0; j < 8; j++) {
    float a0 = bf2f(qA0[j]), a1 = bf2f(qA1[j]);
    float b0 = bf2f(qB0[j]), b1 = bf2f(qB1[j]);
    ssA += a0 * a0 + a1 * a1;
    ssB += b0 * b0 + b1 * b1;
  }
  ssA += __shfl_xor(ssA, 16); ssA += __shfl_xor(ssA, 32);
  ssB += __shfl_xor(ssB, 16); ssB += __shfl_xor(ssB, 32);
  const float kmx = kmax[bh];
  const float mA = sqrtf(ssA) * kmx;
  const float mB = sqrtf(ssB) * kmx;

  f32x4 oA[4] = {}, oB[4] = {};
  float lA = 0.f, lB = 0.f;
  const f32x4 zero = {};

  // fragment read offsets (swizzled; same layout as staged)
  const int kmsk = (lr & 7) << 4;
  const int k00 = lr * 64 + (((lg << 4)) ^ kmsk) / 2;
  const int k01 = lr * 64 + ((64 + (lg << 4)) ^ kmsk) / 2;
  const int k10 = (16 + lr) * 64 + (((lg << 4)) ^ kmsk) / 2;
  const int k11 = (16 + lr) * 64 + ((64 + (lg << 4)) ^ kmsk) / 2;
  const int vmsk = ((lr >> 1) & 3) << 4;
  const int vo = ((lg << 4) ^ vmsk) / 2;

  // ---- stage one 32-kv step (8 x global_load_lds) into buffer bb ----
#define STAGE(s32, bb)                                                          \
  {                                                                             \
    const u16* kgs = Kg + (size_t)(s32) * DH;                                   \
    const u16* vgs = Vg + (s32);                                                \
    _Pragma("unroll")                                                           \
    for (int i = 0; i < 4; i++)                                                 \
      gload_lds16(kgs + (size_t)(i * 8 + krow) * DH + ksoff, &Ks[bb][i * 512]); \
    _Pragma("unroll")                                                           \
    for (int i = 0; i < 4; i++)                                                 \
      gload_lds16(vgs + (size_t)(i * 16 + vrow) * S_LEN + vsoff, &Vs[bb][i * 512]); \
  }

  STAGE(0, 0);  // prologue

  for (int s = 0; s < nst; ++s) {
    const int b = s & 1;
    if (s + 1 < nst) {
      STAGE((s + 1) * 32, b ^ 1);
      asm volatile("s_waitcnt vmcnt(8)" ::: "memory");  // step-s loads landed
    } else {
      asm volatile("s_waitcnt vmcnt(0)" ::: "memory");
    }

    const u16* Kb = Ks[b];
    const u16* Vb = Vs[b];
    bf16x8 kc0 = *(const bf16x8*)&Kb[k00];
    bf16x8 kc1 = *(const bf16x8*)&Kb[k01];
    bf16x8 kc2 = *(const bf16x8*)&Kb[k10];
    bf16x8 kc3 = *(const bf16x8*)&Kb[k11];
    bf16x8 v0 = *(const bf16x8*)&Vb[(lr) * 32 + vo];
    bf16x8 v1 = *(const bf16x8*)&Vb[(16 + lr) * 32 + vo];
    bf16x8 v2 = *(const bf16x8*)&Vb[(32 + lr) * 32 + vo];
    bf16x8 v3 = *(const bf16x8*)&Vb[(48 + lr) * 32 + vo];

    f32x4 s0A = __builtin_amdgcn_mfma_f32_16x16x32_bf16(kc0, qA0, zero, 0, 0, 0);
    s0A = __builtin_amdgcn_mfma_f32_16x16x32_bf16(kc1, qA1, s0A, 0, 0, 0);
    f32x4 s1A = __builtin_amdgcn_mfma_f32_16x16x32_bf16(kc2, qA0, zero, 0, 0, 0);
    s1A = __builtin_amdgcn_mfma_f32_16x16x32_bf16(kc3, qA1, s1A, 0, 0, 0);
    f32x4 s0B = __builtin_amdgcn_mfma_f32_16x16x32_bf16(kc0, qB0, zero, 0, 0, 0);
    s0B = __builtin_amdgcn_mfma_f32_16x16x32_bf16(kc1, qB1, s0B, 0, 0, 0);
    f32x4 s1B = __builtin_amdgcn_mfma_f32_16x16x32_bf16(kc2, qB0, zero, 0, 0, 0);
    s1B = __builtin_amdgcn_mfma_f32_16x16x32_bf16(kc3, qB1, s1B, 0, 0, 0);

    // generic causal mask (auto-passes below the diagonal)
    const int qrelA = qbase + lr - (s << 5) - (lg << 2);
    const int qrelB = qrelA + 16;
    float aA[8], aB[8];
#pragma unroll
    for (int r = 0; r < 4; r++) {
      aA[r]     = (r <= qrelA)      ? s0A[r] : -__builtin_inff();
      aA[4 + r] = (r + 16 <= qrelA) ? s1A[r] : -__builtin_inff();
      aB[r]     = (r <= qrelB)      ? s0B[r] : -__builtin_inff();
      aB[4 + r] = (r + 16 <= qrelB) ? s1B[r] : -__builtin_inff();
    }
    sm_pv(aA, mA, lA, v0, v1, v2, v3, oA);
    sm_pv(aB, mB, lB, v0, v1, v2, v3, oB);
  }
#undef STAGE

  // ---- epilogue: lane holds q=lr, d = dt*16 + lg*4 + r ----
  lA += __shfl_xor(lA, 16); lA += __shfl_xor(lA, 32);
  lB += __shfl_xor(lB, 16); lB += __shfl_xor(lB, 32);
  const float rlA = __builtin_amdgcn_rcpf(lA);
  const float rlB = __builtin_amdgcn_rcpf(lB);

  const int bb = bh >> 4, h = bh & 15;
  const size_t obaseA = ((size_t)bb * S_LEN + qbase + lr) * DM + h * DH;
  const size_t obaseB = obaseA + (size_t)16 * DM;
#pragma unroll
  for (int dt = 0; dt < 4; dt++) {
    u32x2 pkA, pkB;
    pkA.x = pkbf(oA[dt][0] * rlA, oA[dt][1] * rlA);
    pkA.y = pkbf(oA[dt][2] * rlA, oA[dt][3] * rlA);
    pkB.x = pkbf(oB[dt][0] * rlB, oB[dt][1] * rlB);
    pkB.y = pkbf(oB[dt][2] * rlB, oB[dt][3] * rlB);
    *(u32x2*)(Oo + obaseA + dt * 16 + lg * 4) = pkA;
    *(u32x2*)(Oo + obaseB + dt * 16 + lg * 4) = pkB;
  }
}

// ---------------- host launcher ----------------
extern "C" void kernel_launch(void* const* d_in, const int* in_sizes, int n_in,
                              void* d_out, int out_size, void* d_ws, size_t ws_size,
                              hipStream_t stream) {
  const float* x  = (const float*)d_in[0];
  const float* Wq = (const float*)d_in[1];
  const float* bq = (const float*)d_in[2];
  const float* Wk = (const float*)d_in[3];
  const float* bk = (const float*)d_in[4];
  const float* Wv = (const float*)d_in[5];
  const float* bv = (const float*)d_in[6];
  const float* Wo = (const float*)d_in[7];
  const float* bo = (const float*)d_in[8];

  char* ws = (char*)d_ws;
  u16* xb    = (u16*)(ws);                 // 8 MB  [4096,1024] bf16
  u16* wb    = (u16*)(ws + (8u << 20));    // 8 MB  Wq,Wk,Wv,Wo bf16
  u16* Qb    = (u16*)(ws + (16u << 20));   // 8 MB  [B,H,S,Dh]
  u16* Kb    = (u16*)(ws + (24u << 20));   // 8 MB  [B,H,S,Dh]
  u16* Vtb   = (u16*)(ws + (32u << 20));   // 8 MB  [B,H,Dh,S] (s-permuted)
  u16* AOb   = (u16*)(ws + (40u << 20));   // 8 MB  [B*S, DM]
  float2* rt = (float2*)(ws + (48u << 20));            // 512 KB rope table
  float* kmx = (float*)(ws + (48u << 20) + (512u << 10));  // 128 B kmax[32]

  convert_k<<<8192, 256, 0, stream>>>(x, Wq, Wk, Wv, Wo, xb, wb);
  rope_k<<<256, 256, 0, stream>>>(rt, kmx);
  gemm_k<<<768, 256, 0, stream>>>(xb, wb, wb + (1u << 20), wb + (2u << 20),
                                  bq, bk, bv, rt, Qb, Kb, Vtb, 0);
  knorm_k<<<256, 256, 0, stream>>>(Kb, kmx);
  attn_k<<<2048, 64, 0, stream>>>(Qb, Kb, Vtb, AOb, kmx);
  gemm_k<<<256, 256, 0, stream>>>(AOb, wb + (3u << 20), wb + (3u << 20), wb + (3u << 20),
                                  bo, bo, bo, rt, d_out, d_out, d_out, 3);
}

// Round 19
// 149.661 us; speedup vs baseline: 1.1891x; 1.0071x over previous
//
#include <hip/hip_runtime.h>
#include <stdint.h>

#define S_LEN 2048
#define BATCH 2
#define DM 1024
#define NH 16
#define DH 64
#define MROWS 4096  // BATCH * S_LEN

typedef unsigned short u16;
typedef unsigned int u32;
typedef __attribute__((ext_vector_type(8))) short bf16x8;
typedef __attribute__((ext_vector_type(4))) float f32x4;
typedef __attribute__((ext_vector_type(2))) unsigned u32x2;

union pack8 { u32 w[4]; bf16x8 v8; };

__device__ inline u16 f2bf(float f) {
  union { float f; unsigned u; } v; v.f = f;
  unsigned u = v.u;
  unsigned r = u + 0x7fffu + ((u >> 16) & 1u);
  return (u16)(r >> 16);
}

__device__ inline u32 pkbf(float lo, float hi) {
  u32 r;
  asm("v_cvt_pk_bf16_f32 %0, %1, %2" : "=v"(r) : "v"(lo), "v"(hi));
  return r;
}

__device__ inline float bf2f(short s) {
  union { u32 u; float f; } c; c.u = ((u32)(u16)s) << 16;
  return c.f;
}

// async global -> LDS, 16B per lane; LDS dest is wave-uniform base + lane*16
__device__ __forceinline__ void gload_lds16(const u16* g, u16* l) {
  __builtin_amdgcn_global_load_lds(
      (const __attribute__((address_space(1))) u32*)g,
      (__attribute__((address_space(3))) u32*)l, 16, 0, 0);
}

// ---------------- fp32 -> bf16 conversion for x, Wq, Wk, Wv, Wo ----------------
__global__ void convert_k(const float* __restrict__ x, const float* __restrict__ wq,
                          const float* __restrict__ wk, const float* __restrict__ wv,
                          const float* __restrict__ wo, u16* __restrict__ xb,
                          u16* __restrict__ wb) {
  int i = blockIdx.x * blockDim.x + threadIdx.x;
  const int total = (MROWS * DM + 4 * DM * DM) / 4;  // 2,097,152 float4 groups
  if (i >= total) return;
  int e = i * 4;
  const float* src;
  u16* dst;
  if (e < MROWS * DM) {
    src = x + e; dst = xb + e;
  } else {
    int j = e - MROWS * DM;
    int w = j >> 20;
    int o = j & ((1 << 20) - 1);
    src = (w == 0) ? wq + o : (w == 1) ? wk + o : (w == 2) ? wv + o : wo + o;
    dst = wb + j;
  }
  float4 v = *(const float4*)src;
  uint2 r;
  r.x = (unsigned)f2bf(v.x) | ((unsigned)f2bf(v.y) << 16);
  r.y = (unsigned)f2bf(v.z) | ((unsigned)f2bf(v.w) << 16);
  *(uint2*)dst = r;
}

// ---------------- RoPE cos/sin table [S][32]; also zero kmax[32] ----------------
__global__ void rope_k(float2* __restrict__ tab, float* __restrict__ kmax) {
  int i = blockIdx.x * blockDim.x + threadIdx.x;
  if (i < 32) kmax[i] = 0.f;
  if (i >= S_LEN * 32) return;
  int s = i >> 5, p = i & 31;
  float inv = expf(-(float)p * 0.28782313662425575f);  // ln(10000)/32
  float a = (float)s * inv;
  tab[i] = make_float2(cosf(a), sinf(a));
}

// ---------------- per-bh max row norm of K (for static softmax bound) ----------------
__global__ void knorm_k(const u16* __restrict__ K, float* __restrict__ kmax) {
  const int row = blockIdx.x * 256 + threadIdx.x;  // 65536 rows = B*H*S
  const int bh = row >> 11;
  const u16* p = K + (size_t)row * DH;
  float ss = 0.f;
#pragma unroll
  for (int i = 0; i < 8; i++) {
    bf16x8 v = *(const bf16x8*)(p + i * 8);
#pragma unroll
    for (int j = 0; j < 8; j++) { float f = bf2f(v[j]); ss += f * f; }
  }
  float kn = sqrtf(ss);
#pragma unroll
  for (int d = 1; d < 64; d <<= 1) kn = fmaxf(kn, __shfl_xor(kn, d));
  if ((threadIdx.x & 63) == 0)
    atomicMax((unsigned*)(kmax + bh), __float_as_uint(kn));
}

// ---------------- GEMM: C = A @ W^T + bias, fused epilogues (R15/R17 form) ----------------
__launch_bounds__(256)
__global__ void gemm_k(const u16* __restrict__ A,
                       const u16* __restrict__ w0, const u16* __restrict__ w1,
                       const u16* __restrict__ w2,
                       const float* __restrict__ b0, const float* __restrict__ b1,
                       const float* __restrict__ b2,
                       const float2* __restrict__ rope,
                       void* __restrict__ o0, void* __restrict__ o1, void* __restrict__ o2,
                       int mode0) {
  const int mode = mode0 + (int)(blockIdx.x >> 8);
  const int tile = blockIdx.x & 255;
  const int mt = tile >> 3, nt = tile & 7;
  const int mbase = mt * 128, nbase = nt * 128;
  const u16* W = (mode == 1) ? w1 : (mode == 2) ? w2 : w0;
  const float* bias = (mode == 1) ? b1 : (mode == 2) ? b2 : b0;
  void* outp = (mode == 1) ? o1 : (mode == 2) ? o2 : o0;

  __shared__ u16 As[128 * 32];  // 8 KB, linear (global_load_lds writes linearly)
  __shared__ u16 Bs[128 * 32];

  const int t = threadIdx.x;
  const int lane = t & 63, wvi = t >> 6;
  const int lr = lane & 15, lg = lane >> 4;
  const int wm = (wvi >> 1) * 64, wn = (wvi & 1) * 64;

  f32x4 acc[4][4] = {};
  const int srow = t >> 2;        // 0..63 (row within half-tile)
  const int scol = (t & 3) * 8;   // 0,8,16,24 u16

  for (int kk = 0; kk < DM; kk += 32) {
    gload_lds16(A + (size_t)(mbase + srow) * DM + kk + scol, &As[wvi * 512]);
    gload_lds16(A + (size_t)(mbase + 64 + srow) * DM + kk + scol, &As[2048 + wvi * 512]);
    gload_lds16(W + (size_t)(nbase + srow) * DM + kk + scol, &Bs[wvi * 512]);
    gload_lds16(W + (size_t)(nbase + 64 + srow) * DM + kk + scol, &Bs[2048 + wvi * 512]);
    __syncthreads();  // vmcnt(0) drain: tiles staged

    bf16x8 af[4], bfr[4];
#pragma unroll
    for (int mi = 0; mi < 4; mi++)
      af[mi] = *(const bf16x8*)&As[(wm + mi * 16 + lr) * 32 + lg * 8];
#pragma unroll
    for (int ni = 0; ni < 4; ni++)
      bfr[ni] = *(const bf16x8*)&Bs[(wn + ni * 16 + lr) * 32 + lg * 8];
#pragma unroll
    for (int mi = 0; mi < 4; mi++)
#pragma unroll
      for (int ni = 0; ni < 4; ni++)
        acc[mi][ni] = __builtin_amdgcn_mfma_f32_16x16x32_bf16(af[mi], bfr[ni], acc[mi][ni], 0, 0, 0);
    __syncthreads();  // all reads done before next stage overwrites
  }

#pragma unroll
  for (int ni = 0; ni < 4; ni++) {
    const int col = nbase + wn + ni * 16 + lr;
    const float bv = bias[col];
#pragma unroll
    for (int mi = 0; mi < 4; mi++) {
      const int row0 = mbase + wm + mi * 16 + lg * 4;
      f32x4 v = acc[mi][ni];
#pragma unroll
      for (int r = 0; r < 4; r++) {
        float val = v[r] + bv;
        const int row = row0 + r;
        if (mode <= 1) {
          float nb = __shfl_xor(val, 1);
          const int d = col & 63, p = d >> 1, s = row & (S_LEN - 1);
          float2 cs = rope[s * 32 + p];
          float ov = (d & 1) ? (nb * cs.y + val * cs.x) : (val * cs.x - nb * cs.y);
          if (mode == 0) ov *= 0.18033688011112042f;  // 1/sqrt(Dh) * log2(e)
          const int b = row >> 11, h = col >> 6;
          ((u16*)outp)[((size_t)(b * NH + h) * S_LEN + s) * DH + d] = f2bf(ov);
        } else if (mode == 2) {
          const int b = row >> 11, h = col >> 6, d = col & 63, s = row & (S_LEN - 1);
          const int j = s & 31;
          const int pos = (s & ~31) + (((j & 15) >> 2) << 3) + ((j >> 4) << 2) + (j & 3);
          ((u16*)outp)[((size_t)(b * NH + h) * DH + d) * S_LEN + pos] = f2bf(val);
        } else {
          ((float*)outp)[(size_t)row * DM + col] = val;
        }
      }
    }
  }
}

// ---- static-bound softmax + PV for one q-group: accumulate into o[4] ----
__device__ __forceinline__ void sm_pv(const float a[8], float m, float& l,
                                      bf16x8 v0, bf16x8 v1, bf16x8 v2, bf16x8 v3,
                                      f32x4* o) {
  float p[8];
#pragma unroll
  for (int r = 0; r < 8; r++) p[r] = __builtin_amdgcn_exp2f(a[r] - m);
  l += ((p[0] + p[1]) + (p[2] + p[3])) + ((p[4] + p[5]) + (p[6] + p[7]));
  pack8 pu;
  pu.w[0] = pkbf(p[0], p[1]);
  pu.w[1] = pkbf(p[2], p[3]);
  pu.w[2] = pkbf(p[4], p[5]);
  pu.w[3] = pkbf(p[6], p[7]);
  o[0] = __builtin_amdgcn_mfma_f32_16x16x32_bf16(v0, pu.v8, o[0], 0, 0, 0);
  o[1] = __builtin_amdgcn_mfma_f32_16x16x32_bf16(v1, pu.v8, o[1], 0, 0, 0);
  o[2] = __builtin_amdgcn_mfma_f32_16x16x32_bf16(v2, pu.v8, o[2], 0, 0, 0);
  o[3] = __builtin_amdgcn_mfma_f32_16x16x32_bf16(v3, pu.v8, o[3], 0, 0, 0);
}

// ---------------- causal flash attention: R17 base + cross-block kv-split ----------------
// EXACT R17 pipeline (passed; barrier-free 1-wave, K+V LDS dbuf, vmcnt(8)),
// parameterized by kv-step range [s0,s1). Tiles 0..31 run whole (blocks 0..1023,
// R17 epilogue -> AOb). Tiles 32..63 run as TWO blocks (kv halves); each writes
// UNNORMALIZED partials: o (bf16) to the dead xb region, l (fp32) to the dead
// rope region. Merge is a PURE SUM (identical static bound m in both halves) done
// by reduce_k. Makespan: 64 -> 32 steps.
__launch_bounds__(64)
__global__ void attn_k(const u16* __restrict__ Q, const u16* __restrict__ K,
                       const u16* __restrict__ Vt, u16* __restrict__ Oo,
                       const float* __restrict__ kmax,
                       u16* __restrict__ po, float* __restrict__ pl) {
  int bh, tile, s0, s1, pidx = 0, split;
  if (blockIdx.x < 1024) {
    bh = blockIdx.x & 31; tile = (int)(blockIdx.x >> 5);
    s0 = 0; s1 = tile + 1; split = 0;
  } else {
    const int idx = (int)blockIdx.x - 1024;          // 0..2047
    bh = idx & 31; tile = 32 + ((idx >> 5) & 31);
    const int half = idx >> 10;                      // 0/1
    const int nst = tile + 1, h = nst >> 1;
    s0 = half ? h : 0; s1 = half ? nst : h;
    pidx = idx; split = 1;
  }
  const int qbase = tile * 32;
  const int lane = threadIdx.x;
  const int lr = lane & 15, lg = lane >> 4;

  __shared__ u16 Ks[2][2048];                  // [buf][32 x 64] bf16, swizzled
  __shared__ u16 Vs[2][2048];                  // [buf][64 x 32] bf16, swizzled

  const u16* Kg = K + (size_t)bh * S_LEN * DH;
  const u16* Vg = Vt + (size_t)bh * DH * S_LEN;

  // staging constants (lane-static; R17-proven)
  const int krow = lane >> 3;                          // + 8*i
  const int ksoff = ((((lane & 7) << 4) ^ ((lane >> 3) << 4)) >> 1);  // u16
  const int vrow = lane >> 2;                          // + 16*i
  const int vsoff = ((((lane & 3) << 4) ^ (((lane >> 3) & 3) << 4)) >> 1);

  // ---- Q fragments + static softmax bound (identical across halves) ----
  const size_t qoff = ((size_t)bh * S_LEN + qbase + lr) * DH + lg * 8;
  const bf16x8 qA0 = *(const bf16x8*)(Q + qoff);
  const bf16x8 qA1 = *(const bf16x8*)(Q + qoff + 32);
  const bf16x8 qB0 = *(const bf16x8*)(Q + qoff + 16 * DH);
  const bf16x8 qB1 = *(const bf16x8*)(Q + qoff + 16 * DH + 32);

  float ssA = 0.f, ssB = 0.f;
#pragma unroll
  for (int j = 0; j < 8; j++) {
    float a0 = bf2f(qA0[j]), a1 = bf2f(qA1[j]);
    float b0 = bf2f(qB0[j]), b1 = bf2f(qB1[j]);
    ssA += a0 * a0 + a1 * a1;
    ssB += b0 * b0 + b1 * b1;
  }
  ssA += __shfl_xor(ssA, 16); ssA += __shfl_xor(ssA, 32);
  ssB += __shfl_xor(ssB, 16); ssB += __shfl_xor(ssB, 32);
  const float kmx = kmax[bh];
  const float mA = sqrtf(ssA) * kmx;
  const float mB = sqrtf(ssB) * kmx;

  f32x4 oA[4] = {}, oB[4] = {};
  float lA = 0.f, lB = 0.f;
  const f32x4 zero = {};

  // fragment read offsets (swizzled; same layout as staged)
  const int kmsk = (lr & 7) << 4;
  const int k00 = lr * 64 + (((lg << 4)) ^ kmsk) / 2;
  const int k01 = lr * 64 + ((64 + (lg << 4)) ^ kmsk) / 2;
  const int k10 = (16 + lr) * 64 + (((lg << 4)) ^ kmsk) / 2;
  const int k11 = (16 + lr) * 64 + ((64 + (lg << 4)) ^ kmsk) / 2;
  const int vmsk = ((lr >> 1) & 3) << 4;
  const int vo = ((lg << 4) ^ vmsk) / 2;

#define STAGE(s32, bb)                                                          \
  {                                                                             \
    const u16* kgs = Kg + (size_t)(s32) * DH;                                   \
    const u16* vgs = Vg + (s32);                                                \
    _Pragma("unroll")                                                           \
    for (int i = 0; i < 4; i++)                                                 \
      gload_lds16(kgs + (size_t)(i * 8 + krow) * DH + ksoff, &Ks[bb][i * 512]); \
    _Pragma("unroll")                                                           \
    for (int i = 0; i < 4; i++)                                                 \
      gload_lds16(vgs + (size_t)(i * 16 + vrow) * S_LEN + vsoff, &Vs[bb][i * 512]); \
  }

  STAGE(s0 * 32, s0 & 1);  // prologue

  for (int s = s0; s < s1; ++s) {
    const int b = s & 1;
    if (s + 1 < s1) {
      STAGE((s + 1) * 32, b ^ 1);
      asm volatile("s_waitcnt vmcnt(8)" ::: "memory");  // step-s loads landed
    } else {
      asm volatile("s_waitcnt vmcnt(0)" ::: "memory");
    }

    const u16* Kb = Ks[b];
    const u16* Vb = Vs[b];
    bf16x8 kc0 = *(const bf16x8*)&Kb[k00];
    bf16x8 kc1 = *(const bf16x8*)&Kb[k01];
    bf16x8 kc2 = *(const bf16x8*)&Kb[k10];
    bf16x8 kc3 = *(const bf16x8*)&Kb[k11];
    bf16x8 v0 = *(const bf16x8*)&Vb[(lr) * 32 + vo];
    bf16x8 v1 = *(const bf16x8*)&Vb[(16 + lr) * 32 + vo];
    bf16x8 v2 = *(const bf16x8*)&Vb[(32 + lr) * 32 + vo];
    bf16x8 v3 = *(const bf16x8*)&Vb[(48 + lr) * 32 + vo];

    f32x4 s0A = __builtin_amdgcn_mfma_f32_16x16x32_bf16(kc0, qA0, zero, 0, 0, 0);
    s0A = __builtin_amdgcn_mfma_f32_16x16x32_bf16(kc1, qA1, s0A, 0, 0, 0);
    f32x4 s1A = __builtin_amdgcn_mfma_f32_16x16x32_bf16(kc2, qA0, zero, 0, 0, 0);
    s1A = __builtin_amdgcn_mfma_f32_16x16x32_bf16(kc3, qA1, s1A, 0, 0, 0);
    f32x4 s0B = __builtin_amdgcn_mfma_f32_16x16x32_bf16(kc0, qB0, zero, 0, 0, 0);
    s0B = __builtin_amdgcn_mfma_f32_16x16x32_bf16(kc1, qB1, s0B, 0, 0, 0);
    f32x4 s1B = __builtin_amdgcn_mfma_f32_16x16x32_bf16(kc2, qB0, zero, 0, 0, 0);
    s1B = __builtin_amdgcn_mfma_f32_16x16x32_bf16(kc3, qB1, s1B, 0, 0, 0);

    // generic causal mask (auto-passes below the diagonal)
    const int qrelA = qbase + lr - (s << 5) - (lg << 2);
    const int qrelB = qrelA + 16;
    float aA[8], aB[8];
#pragma unroll
    for (int r = 0; r < 4; r++) {
      aA[r]     = (r <= qrelA)      ? s0A[r] : -__builtin_inff();
      aA[4 + r] = (r + 16 <= qrelA) ? s1A[r] : -__builtin_inff();
      aB[r]     = (r <= qrelB)      ? s0B[r] : -__builtin_inff();
      aB[4 + r] = (r + 16 <= qrelB) ? s1B[r] : -__builtin_inff();
    }
    sm_pv(aA, mA, lA, v0, v1, v2, v3, oA);
    sm_pv(aB, mB, lB, v0, v1, v2, v3, oB);
  }
#undef STAGE

  // ---- cross-lane l reduce (both paths) ----
  lA += __shfl_xor(lA, 16); lA += __shfl_xor(lA, 32);
  lB += __shfl_xor(lB, 16); lB += __shfl_xor(lB, 32);

  if (!split) {
    const float rlA = __builtin_amdgcn_rcpf(lA);
    const float rlB = __builtin_amdgcn_rcpf(lB);
    const int bb = bh >> 4, h = bh & 15;
    const size_t obaseA = ((size_t)bb * S_LEN + qbase + lr) * DM + h * DH;
    const size_t obaseB = obaseA + (size_t)16 * DM;
#pragma unroll
    for (int dt = 0; dt < 4; dt++) {
      u32x2 pkA, pkB;
      pkA.x = pkbf(oA[dt][0] * rlA, oA[dt][1] * rlA);
      pkA.y = pkbf(oA[dt][2] * rlA, oA[dt][3] * rlA);
      pkB.x = pkbf(oB[dt][0] * rlB, oB[dt][1] * rlB);
      pkB.y = pkbf(oB[dt][2] * rlB, oB[dt][3] * rlB);
      *(u32x2*)(Oo + obaseA + dt * 16 + lg * 4) = pkA;
      *(u32x2*)(Oo + obaseB + dt * 16 + lg * 4) = pkB;
    }
  } else {
    // partials: po[pidx][qlocal*64 + d] bf16 (unnormalized), pl[pidx*32 + qlocal]
    u16* pb = po + (size_t)pidx * 2048;
#pragma unroll
    for (int dt = 0; dt < 4; dt++) {
      const int dbase = dt * 16 + lg * 4;
      u32x2 pkA, pkB;
      pkA.x = pkbf(oA[dt][0], oA[dt][1]);
      pkA.y = pkbf(oA[dt][2], oA[dt][3]);
      pkB.x = pkbf(oB[dt][0], oB[dt][1]);
      pkB.y = pkbf(oB[dt][2], oB[dt][3]);
      *(u32x2*)(pb + lr * 64 + dbase) = pkA;
      *(u32x2*)(pb + (16 + lr) * 64 + dbase) = pkB;
    }
    if (lg == 0) {
      pl[pidx * 32 + lr] = lA;
      pl[pidx * 32 + 16 + lr] = lB;
    }
  }
}

// ---------------- merge split-tile partials: out = (o0+o1)/(l0+l1) ----------------
__global__ void reduce_k(const u16* __restrict__ po, const float* __restrict__ pl,
                         u16* __restrict__ Oo) {
  const int i = blockIdx.x * 256 + threadIdx.x;   // 262144 total
  const int dg = i & 7;                           // 8 bf16 per thread
  const int q = (i >> 3) & 31;
  const int tt = (i >> 8) & 31;
  const int bh = i >> 13;                         // 0..31
  const int p0 = tt * 32 + bh, p1 = 1024 + p0;
  const bf16x8 a = *(const bf16x8*)(po + (size_t)p0 * 2048 + q * 64 + dg * 8);
  const bf16x8 b = *(const bf16x8*)(po + (size_t)p1 * 2048 + q * 64 + dg * 8);
  const float rl = __builtin_amdgcn_rcpf(pl[p0 * 32 + q] + pl[p1 * 32 + q]);
  pack8 r;
#pragma unroll
  for (int j = 0; j < 4; j++)
    r.w[j] = pkbf((bf2f(a[2 * j]) + bf2f(b[2 * j])) * rl,
                  (bf2f(a[2 * j + 1]) + bf2f(b[2 * j + 1])) * rl);
  const int s = (32 + tt) * 32 + q;
  u16* dst = Oo + ((size_t)(bh >> 4) * S_LEN + s) * DM + (bh & 15) * DH + dg * 8;
  *(bf16x8*)dst = r.v8;
}

// ---------------- host launcher ----------------
extern "C" void kernel_launch(void* const* d_in, const int* in_sizes, int n_in,
                              void* d_out, int out_size, void* d_ws, size_t ws_size,
                              hipStream_t stream) {
  const float* x  = (const float*)d_in[0];
  const float* Wq = (const float*)d_in[1];
  const float* bq = (const float*)d_in[2];
  const float* Wk = (const float*)d_in[3];
  const float* bk = (const float*)d_in[4];
  const float* Wv = (const float*)d_in[5];
  const float* bv = (const float*)d_in[6];
  const float* Wo = (const float*)d_in[7];
  const float* bo = (const float*)d_in[8];

  char* ws = (char*)d_ws;
  u16* xb    = (u16*)(ws);                 // 8 MB  [4096,1024] bf16 (dead after QKV gemm -> po)
  u16* wb    = (u16*)(ws + (8u << 20));    // 8 MB  Wq,Wk,Wv,Wo bf16
  u16* Qb    = (u16*)(ws + (16u << 20));   // 8 MB  [B,H,S,Dh]
  u16* Kb    = (u16*)(ws + (24u << 20));   // 8 MB  [B,H,S,Dh]
  u16* Vtb   = (u16*)(ws + (32u << 20));   // 8 MB  [B,H,Dh,S] (s-permuted)
  u16* AOb   = (u16*)(ws + (40u << 20));   // 8 MB  [B*S, DM]
  float2* rt = (float2*)(ws + (48u << 20));            // 512 KB rope table (dead after gemm -> pl)
  float* kmx = (float*)(ws + (48u << 20) + (512u << 10));  // 128 B kmax[32]

  u16* po   = xb;            // 2048 halves x 4 KB bf16 partial o (reuses xb)
  float* pl = (float*)rt;    // 2048 x 32 fp32 partial l (reuses rope table)

  convert_k<<<8192, 256, 0, stream>>>(x, Wq, Wk, Wv, Wo, xb, wb);
  rope_k<<<256, 256, 0, stream>>>(rt, kmx);
  gemm_k<<<768, 256, 0, stream>>>(xb, wb, wb + (1u << 20), wb + (2u << 20),
                                  bq, bk, bv, rt, Qb, Kb, Vtb, 0);
  knorm_k<<<256, 256, 0, stream>>>(Kb, kmx);
  attn_k<<<3072, 64, 0, stream>>>(Qb, Kb, Vtb, AOb, kmx, po, pl);
  reduce_k<<<1024, 256, 0, stream>>>(po, pl, AOb);
  gemm_k<<<256, 256, 0, stream>>>(AOb, wb + (3u << 20), wb + (3u << 20), wb + (3u << 20),
                                  bo, bo, bo, rt, d_out, d_out, d_out, 3);
}